// Round 1
// baseline (8405.334 us; speedup 1.0000x reference)
//
#include <hip/hip_runtime.h>
#include <stdint.h>

#define TSTEPS 512
#define BATCH  64
#define HDIM   512
#define GATE   2048
#define ACTMAT (BATCH * HDIM)   // 32768 activations per timestep matrix
#define NWGL   64               // workgroups per layer

typedef __attribute__((ext_vector_type(8))) short bf16x8;
typedef __attribute__((ext_vector_type(4))) float f32x4;

__device__ __forceinline__ unsigned short f2bf(float f) {
  union { float f; uint32_t u; } v; v.f = f;
  uint32_t r = v.u + 0x7FFFu + ((v.u >> 16) & 1u);   // RNE
  return (unsigned short)(r >> 16);
}
__device__ __forceinline__ float bf2f(unsigned short s) {
  union { uint32_t u; float f; } v; v.u = ((uint32_t)s) << 16;
  return v.f;
}
__device__ __forceinline__ float fsigmoid(float x) {
  return 1.0f / (1.0f + __expf(-x));
}

// ---------------- pre-kernels ----------------

__global__ void init_buffers(unsigned short* h0, unsigned short* h1, int* flags) {
  int i = blockIdx.x * blockDim.x + threadIdx.x;
  if (i < ACTMAT) { h0[i] = 0; h1[i] = 0; }          // h*, c* initial state = 0 (bf16 zero = 0x0000)
  if (i < 2 * (TSTEPS + 1)) flags[i] = 0;            // re-zero flags EVERY launch (graph replay safe)
}

__global__ void convert_x(const float* __restrict__ x, unsigned short* __restrict__ xb) {
  size_t i = (size_t)(blockIdx.x * blockDim.x + threadIdx.x) * 4;
  float4 v = *(const float4*)(x + i);
  ushort4 o = make_ushort4(f2bf(v.x), f2bf(v.y), f2bf(v.z), f2bf(v.w));
  *(ushort4*)(xb + i) = o;
}

// Fuse [Wi | Wh] into [GATE][1024] and split each weight into bf16 hi + lo residual.
__global__ void split_w(const float* __restrict__ Wi, const float* __restrict__ Wh,
                        unsigned short* __restrict__ Whi, unsigned short* __restrict__ Wlo) {
  int i = blockIdx.x * blockDim.x + threadIdx.x;     // over GATE*1024
  int G = i >> 10, k = i & 1023;
  float w = (k < 512) ? Wi[((size_t)G << 9) + k] : Wh[((size_t)G << 9) + (k - 512)];
  unsigned short hi = f2bf(w);
  Whi[i] = hi;
  Wlo[i] = f2bf(w - bf2f(hi));
}

// ---------------- persistent recurrence kernel ----------------
// 128 WGs: blockIdx>>6 = layer, blockIdx&63 = column slice (8 h-cols, 32 gate cols).
// Gate column ordering inside a WG: n = 4*(j-j0) + q, q in {i,o,z,f} -> cell update is
// 3x shfl_xor within 4-lane groups. Weights (hi+lo bf16) LDS-resident, XOR-swizzled
// 16B units for conflict-free ds_read_b128. c-state lives in registers all 512 steps.
// Cross-WG sync: full-history h buffers + per-(layer,t) counting flags
// (release atomicAdd / acquire spin, agent scope).

__global__ __launch_bounds__(128, 1)
void sublstm_persistent(const unsigned short* __restrict__ xb,
                        unsigned short* h0, unsigned short* h1,
                        const unsigned short* __restrict__ W0hi, const unsigned short* __restrict__ W0lo,
                        const unsigned short* __restrict__ W1hi, const unsigned short* __restrict__ W1lo,
                        const float* __restrict__ bi0, const float* __restrict__ bi1,
                        float* __restrict__ out, int* flags)
{
  __shared__ unsigned short wlds[2][32][1024];       // 128 KiB: [hi/lo][col][k]

  const int wg    = blockIdx.x;
  const int layer = wg >> 6;
  const int slice = wg & 63;
  const int j0    = slice << 3;                      // first owned h-column
  const int tid   = threadIdx.x;
  const int lane  = tid & 63;
  const int wv    = tid >> 6;                        // wave 0/1

  const unsigned short* Whi = layer ? W1hi : W0hi;
  const unsigned short* Wlo = layer ? W1lo : W0lo;
  const float* bi = layer ? bi1 : bi0;

  // stage weight slice into LDS (16B units, unit index swizzled by col&7)
  for (int idx = tid; idx < 8192; idx += 128) {
    int p = idx >> 12;                               // hi/lo panel
    int n = (idx >> 7) & 31;                         // local col
    int u = idx & 127;                               // 16B unit within col
    int G = ((n & 3) << 9) + j0 + (n >> 2);          // gate row = q*512 + j
    const unsigned short* s = (p ? Wlo : Whi) + ((size_t)G << 10) + ((size_t)u << 3);
    uint4 v = *(const uint4*)s;
    *(uint4*)&wlds[p][n][(u ^ (n & 7)) << 3] = v;
  }
  __syncthreads();

  const int c15 = lane & 15;
  const int g4  = lane >> 4;
  const int n0 = c15, n1 = 16 + c15;
  const float bias0 = bi[((n0 & 3) << 9) + j0 + (n0 >> 2)];
  const float bias1 = bi[((n1 & 3) << 9) + j0 + (n1 >> 2)];
  const unsigned short* bb_h0 = &wlds[0][n0][0];
  const unsigned short* bb_l0 = &wlds[1][n0][0];
  const unsigned short* bb_h1 = &wlds[0][n1][0];
  const unsigned short* bb_l1 = &wlds[1][n1][0];
  const int sw0 = n0 & 7, sw1 = n1 & 7;
  const size_t aoff0 = (size_t)((wv << 5) + c15) * HDIM + (g4 << 3);  // A row (lane&15), k-subgroup
  const size_t aoff1 = aoff0 + (size_t)16 * HDIM;

  float cst[2][2][4] = {};                           // c-state, static-indexed only
  int* flags0 = flags;
  int* flags1 = flags + (TSTEPS + 1);
  const bool owner = ((lane & 3) == 0);              // q==0 lanes own the cell update
  const int jbase0 = j0 + (c15 >> 2);
  const int brow0  = (wv << 5) + (g4 << 2);

#define KSTEP(AB, KK, KB) do {                                                        \
    bf16x8 a0 = *(const bf16x8*)((AB) + aoff0 + ((KK) << 5));                         \
    bf16x8 a1 = *(const bf16x8*)((AB) + aoff1 + ((KK) << 5));                         \
    int u_ = ((KB) << 2) + g4;                                                        \
    bf16x8 bh0 = *(const bf16x8*)(bb_h0 + ((u_ ^ sw0) << 3));                         \
    bf16x8 bl0 = *(const bf16x8*)(bb_l0 + ((u_ ^ sw0) << 3));                         \
    bf16x8 bh1 = *(const bf16x8*)(bb_h1 + ((u_ ^ sw1) << 3));                         \
    bf16x8 bl1 = *(const bf16x8*)(bb_l1 + ((u_ ^ sw1) << 3));                         \
    acc00 = __builtin_amdgcn_mfma_f32_16x16x32_bf16(a0, bh0, acc00, 0, 0, 0);         \
    acc00 = __builtin_amdgcn_mfma_f32_16x16x32_bf16(a0, bl0, acc00, 0, 0, 0);         \
    acc01 = __builtin_amdgcn_mfma_f32_16x16x32_bf16(a0, bh1, acc01, 0, 0, 0);         \
    acc01 = __builtin_amdgcn_mfma_f32_16x16x32_bf16(a0, bl1, acc01, 0, 0, 0);         \
    acc10 = __builtin_amdgcn_mfma_f32_16x16x32_bf16(a1, bh0, acc10, 0, 0, 0);         \
    acc10 = __builtin_amdgcn_mfma_f32_16x16x32_bf16(a1, bl0, acc10, 0, 0, 0);         \
    acc11 = __builtin_amdgcn_mfma_f32_16x16x32_bf16(a1, bh1, acc11, 0, 0, 0);         \
    acc11 = __builtin_amdgcn_mfma_f32_16x16x32_bf16(a1, bl1, acc11, 0, 0, 0);         \
  } while (0)

  for (int t = 0; t < TSTEPS; ++t) {
    // ---- wait for dependencies (thread 0 spins, others park at barrier) ----
    if (tid == 0) {
      if (layer == 0) {
        if (t > 0)
          while (__hip_atomic_load(&flags0[t], __ATOMIC_RELAXED, __HIP_MEMORY_SCOPE_AGENT) < NWGL)
            __builtin_amdgcn_s_sleep(2);
      } else {
        while (__hip_atomic_load(&flags0[t + 1], __ATOMIC_RELAXED, __HIP_MEMORY_SCOPE_AGENT) < NWGL)
          __builtin_amdgcn_s_sleep(2);
        if (t > 0)
          while (__hip_atomic_load(&flags1[t], __ATOMIC_RELAXED, __HIP_MEMORY_SCOPE_AGENT) < NWGL)
            __builtin_amdgcn_s_sleep(2);
      }
      __threadfence();                               // acquire: invalidate stale cache lines
    }
    __syncthreads();

    // A operands: layer0 = [x_t | h0_t], layer1 = [out0_t (= h0_{t+1}) | h1_t]
    const unsigned short* srcA = layer ? (h0 + (size_t)(t + 1) * ACTMAT) : (xb + (size_t)t * ACTMAT);
    const unsigned short* srcB = layer ? (h1 + (size_t)t * ACTMAT) : (h0 + (size_t)t * ACTMAT);

    f32x4 acc00 = {}, acc01 = {}, acc10 = {}, acc11 = {};

    #pragma unroll 4
    for (int kb = 0; kb < 16; ++kb) KSTEP(srcA, kb, kb);
    #pragma unroll 4
    for (int kb = 16; kb < 32; ++kb) KSTEP(srcB, kb - 16, kb);

    // ---- epilogue: gates -> cell update -> h ----
    unsigned short* hnext = (layer ? h1 : h0) + (size_t)(t + 1) * ACTMAT;
    float* outp = out + (size_t)t * ACTMAT;

    #pragma unroll
    for (int m = 0; m < 2; ++m) {
      #pragma unroll
      for (int nf = 0; nf < 2; ++nf) {
        f32x4 av = (m == 0) ? (nf == 0 ? acc00 : acc01) : (nf == 0 ? acc10 : acc11);
        float bias = nf ? bias1 : bias0;
        #pragma unroll
        for (int r = 0; r < 4; ++r) {
          float gg = fsigmoid(av[r] + bias);         // this lane's gate (quadrant q = lane&3)
          float og = __shfl_xor(gg, 1);              // q0 lane gathers o (q1)
          float zg = __shfl_xor(gg, 2);              // z (q2)
          float fg = __shfl_xor(gg, 3);              // f (q3)
          float cv = cst[m][nf][r] * fg + zg - gg;   // c*f + z - i
          cst[m][nf][r] = cv;
          float hh = fsigmoid(cv) - og;              // sigmoid(c) - o
          if (owner) {
            int b = brow0 + (m << 4) + r;
            int j = jbase0 + (nf << 2);
            hnext[(size_t)b * HDIM + j] = f2bf(hh);
            if (layer) outp[(size_t)b * HDIM + j] = hh;
          }
        }
      }
    }

    __syncthreads();                                 // drains all waves' stores (vmcnt(0) at barrier)
    if (tid == 0) {
      __threadfence();                               // release: make stores device-visible
      atomicAdd(layer ? &flags1[t + 1] : &flags0[t + 1], 1);
    }
  }
#undef KSTEP
}

// ---------------- launch ----------------

extern "C" void kernel_launch(void* const* d_in, const int* in_sizes, int n_in,
                              void* d_out, int out_size, void* d_ws, size_t ws_size,
                              hipStream_t stream) {
  (void)in_sizes; (void)n_in; (void)out_size; (void)ws_size;
  const float* x   = (const float*)d_in[0];
  const float* Wi0 = (const float*)d_in[1];
  const float* bi0 = (const float*)d_in[2];
  const float* Wh0 = (const float*)d_in[3];
  const float* Wi1 = (const float*)d_in[4];
  const float* bi1 = (const float*)d_in[5];
  const float* Wh1 = (const float*)d_in[6];
  float* out = (float*)d_out;

  char* ws = (char*)d_ws;
  size_t off = 0;
  auto take = [&](size_t bytes) -> void* {
    void* p = ws + off;
    off += (bytes + 255) & ~(size_t)255;
    return p;
  };
  unsigned short* xb   = (unsigned short*)take((size_t)TSTEPS * ACTMAT * 2);        // 33.5 MB
  unsigned short* h0   = (unsigned short*)take((size_t)(TSTEPS + 1) * ACTMAT * 2);  // 33.6 MB
  unsigned short* h1   = (unsigned short*)take((size_t)(TSTEPS + 1) * ACTMAT * 2);  // 33.6 MB
  unsigned short* W0hi = (unsigned short*)take((size_t)GATE * 1024 * 2);            // 4 MB x4
  unsigned short* W0lo = (unsigned short*)take((size_t)GATE * 1024 * 2);
  unsigned short* W1hi = (unsigned short*)take((size_t)GATE * 1024 * 2);
  unsigned short* W1lo = (unsigned short*)take((size_t)GATE * 1024 * 2);
  int* flags           = (int*)take((size_t)2 * (TSTEPS + 1) * sizeof(int));

  init_buffers<<<dim3(128), dim3(256), 0, stream>>>(h0, h1, flags);
  convert_x<<<dim3(16384), dim3(256), 0, stream>>>(x, xb);
  split_w<<<dim3(8192), dim3(256), 0, stream>>>(Wi0, Wh0, W0hi, W0lo);
  split_w<<<dim3(8192), dim3(256), 0, stream>>>(Wi1, Wh1, W1hi, W1lo);
  sublstm_persistent<<<dim3(128), dim3(128), 0, stream>>>(
      xb, h0, h1, W0hi, W0lo, W1hi, W1lo, bi0, bi1, out, flags);
}

// Round 3
// 5789.065 us; speedup vs baseline: 1.4519x; 1.4519x over previous
//
#include <hip/hip_runtime.h>
#include <stdint.h>

#define TSTEPS 512
#define BATCH  64
#define HDIM   512
#define GATE   2048
#define ACTMAT (BATCH * HDIM)   // 32768 activations per timestep matrix
#define NWGL   64               // workgroups per layer
#define FSTRIDE ((TSTEPS + 1) * NWGL)

typedef __attribute__((ext_vector_type(8))) short bf16x8;
typedef __attribute__((ext_vector_type(4))) float f32x4;

__device__ __forceinline__ unsigned short f2bf(float f) {
  union { float f; uint32_t u; } v; v.f = f;
  uint32_t r = v.u + 0x7FFFu + ((v.u >> 16) & 1u);   // RNE
  return (unsigned short)(r >> 16);
}
__device__ __forceinline__ float bf2f(unsigned short s) {
  union { uint32_t u; float f; } v; v.u = ((uint32_t)s) << 16;
  return v.f;
}
__device__ __forceinline__ float fsigmoid(float x) {
  return 1.0f / (1.0f + __expf(-x));
}

// ---------------- pre-kernels ----------------

__global__ void init_buffers(unsigned short* h0, unsigned short* h1, int* flags) {
  int i = blockIdx.x * blockDim.x + threadIdx.x;
  if (i < ACTMAT) { h0[i] = 0; h1[i] = 0; }          // h,c initial state = 0
  if (i < 2 * FSTRIDE)                               // re-init flags EVERY launch
    flags[i] = ((i % FSTRIDE) < NWGL) ? 1 : 0;       // t=0 flags pre-set (h[0] is zeros)
}

__global__ void convert_x(const float* __restrict__ x, unsigned short* __restrict__ xb) {
  size_t i = (size_t)(blockIdx.x * blockDim.x + threadIdx.x) * 4;
  float4 v = *(const float4*)(x + i);
  ushort4 o = make_ushort4(f2bf(v.x), f2bf(v.y), f2bf(v.z), f2bf(v.w));
  *(ushort4*)(xb + i) = o;
}

// Fuse [Wi | Wh] into [GATE][1024]; split each weight into bf16 hi + lo residual.
__global__ void split_w(const float* __restrict__ Wi, const float* __restrict__ Wh,
                        unsigned short* __restrict__ Whi, unsigned short* __restrict__ Wlo) {
  int i = blockIdx.x * blockDim.x + threadIdx.x;     // over GATE*1024
  int G = i >> 10, k = i & 1023;
  float w = (k < 512) ? Wi[((size_t)G << 9) + k] : Wh[((size_t)G << 9) + (k - 512)];
  unsigned short hi = f2bf(w);
  Whi[i] = hi;
  Wlo[i] = f2bf(w - bf2f(hi));
}

// ---------------- persistent recurrence kernel ----------------
// 128 WGs x 256 threads: blockIdx>>6 = layer, blockIdx&63 = slice (8 h-cols, 32 gate rows).
// Transposed GEMM: D[n][b] = sum_k W[n][k]*Act[b][k] via mfma(A=W_frag, B=Act_frag).
// A frag: lane holds A[lane&15][g4*8+j]; B frag: lane holds B[g4*8+j][lane&15]  (g4=lane>>4)
// -> BOTH operands need the per-lane-group k-offset g4*8 (round-2 bug: missing on B).
// C/D: col=lane&15 -> b, row=4*g4+reg -> n; n = 4*j_local + q puts all 4 gate quadrants
// of one (b,j) into one lane's 4 acc regs: zero-shuffle epilogue. Weights (hi+lo)
// LDS-resident, 4-bit XOR swizzle. Cross-WG h exchange: relaxed agent-scope atomics
// (bypass L1/L2, coherent at memory-side L3); per-WG flags, lane-parallel poll + __all.

__global__ __launch_bounds__(256, 1)
void sublstm_persistent(const unsigned short* __restrict__ xb,
                        unsigned short* h0, unsigned short* h1,
                        const unsigned short* __restrict__ W0hi, const unsigned short* __restrict__ W0lo,
                        const unsigned short* __restrict__ W1hi, const unsigned short* __restrict__ W1lo,
                        const float* __restrict__ bi0, const float* __restrict__ bi1,
                        float* __restrict__ out, int* flags)
{
  __shared__ unsigned short wlds[2][32][1024];       // 128 KiB: [hi/lo][n][k]

  const int wg    = blockIdx.x;
  const int layer = wg >> 6;
  const int slice = wg & 63;
  const int j0    = slice << 3;                      // first owned h-column
  const int tid   = threadIdx.x;
  const int lane  = tid & 63;
  const int wv    = tid >> 6;                        // wave 0..3 (b-tile)

  const unsigned short* Whi = layer ? W1hi : W0hi;
  const unsigned short* Wlo = layer ? W1lo : W0lo;
  const float* bi = layer ? bi1 : bi0;

  // stage weight slice into LDS (16B units, unit index XOR-swizzled by n&15)
  for (int idx = tid; idx < 8192; idx += 256) {
    int p = idx >> 12;                               // hi/lo panel
    int n = (idx >> 7) & 31;                         // local gate row (n = q + 4*j_local)
    int u = idx & 127;                               // 16B unit within row
    int G = ((n & 3) << 9) + j0 + (n >> 2);          // gate row = q*512 + j
    const unsigned short* s = (p ? Wlo : Whi) + ((size_t)G << 10) + ((size_t)u << 3);
    *(uint4*)&wlds[p][n][(u ^ (n & 15)) << 3] = *(const uint4*)s;
  }
  __syncthreads();

  const int c15 = lane & 15;
  const int g4  = lane >> 4;
  const int n0 = c15, n1 = 16 + c15;
  const int sw = c15;                                // XOR swizzle key (n0&15 == n1&15)
  const int b    = (wv << 4) + c15;                  // batch row this lane owns
  const int jcol0 = j0 + g4;                         // h-col, tile 0
  const size_t arow = (size_t)b * HDIM;              // activation row offset (per 512-wide half)
  const size_t hoff0 = arow + jcol0;
  const size_t hoff1 = hoff0 + 4;                    // tile 1: j = jcol0 + 4

  const float b00 = bi[jcol0],        b01 = bi[512 + jcol0];
  const float b02 = bi[1024 + jcol0], b03 = bi[1536 + jcol0];
  const float b10 = bi[jcol0 + 4],        b11 = bi[512 + jcol0 + 4];
  const float b12 = bi[1024 + jcol0 + 4], b13 = bi[1536 + jcol0 + 4];

  int* flags0 = flags;
  int* flags1 = flags + FSTRIDE;
  int* myflag = layer ? flags1 : flags0;

  float c0 = 0.0f, c1 = 0.0f;                        // cell state, lives in regs all 512 steps

#define KHALF(AP, UBASE, COH) do {                                                     \
    const unsigned short* ap_ = (AP) + arow + (g4 << 3);  /* B-frag k-offset: g4*8 */  \
    _Pragma("unroll")                                                                  \
    for (int kk = 0; kk < 16; ++kk) {                                                  \
      bf16x8 a;                                                                        \
      if (COH) {                                                                       \
        union { unsigned long long q[2]; bf16x8 v; } uu;                               \
        const unsigned long long* p8 = (const unsigned long long*)(ap_ + (kk << 5));   \
        uu.q[0] = __hip_atomic_load(p8,     __ATOMIC_RELAXED, __HIP_MEMORY_SCOPE_AGENT);\
        uu.q[1] = __hip_atomic_load(p8 + 1, __ATOMIC_RELAXED, __HIP_MEMORY_SCOPE_AGENT);\
        a = uu.v;                                                                      \
      } else {                                                                         \
        a = *(const bf16x8*)(ap_ + (kk << 5));                                         \
      }                                                                                \
      int u_ = ((UBASE) + (kk << 2) + g4) ^ sw;                                        \
      bf16x8 wh0 = *(const bf16x8*)&wlds[0][n0][u_ << 3];                              \
      bf16x8 wl0 = *(const bf16x8*)&wlds[1][n0][u_ << 3];                              \
      bf16x8 wh1 = *(const bf16x8*)&wlds[0][n1][u_ << 3];                              \
      bf16x8 wl1 = *(const bf16x8*)&wlds[1][n1][u_ << 3];                              \
      acc0 = __builtin_amdgcn_mfma_f32_16x16x32_bf16(wh0, a, acc0, 0, 0, 0);           \
      acc0 = __builtin_amdgcn_mfma_f32_16x16x32_bf16(wl0, a, acc0, 0, 0, 0);           \
      acc1 = __builtin_amdgcn_mfma_f32_16x16x32_bf16(wh1, a, acc1, 0, 0, 0);           \
      acc1 = __builtin_amdgcn_mfma_f32_16x16x32_bf16(wl1, a, acc1, 0, 0, 0);           \
    }                                                                                  \
  } while (0)

#define WAIT_FLAGS(FP) do {                                                            \
    if (tid < 64) {                                                                    \
      while (!__all(__hip_atomic_load((FP) + tid, __ATOMIC_RELAXED,                    \
                                      __HIP_MEMORY_SCOPE_AGENT) != 0))                 \
        __builtin_amdgcn_s_sleep(2);                                                   \
    }                                                                                  \
    __syncthreads();                                                                   \
  } while (0)

#define EPILOGUE(T) do {                                                               \
    unsigned short* hn = (layer ? h1 : h0) + (size_t)((T) + 1) * ACTMAT;               \
    float gi0 = fsigmoid(acc0[0] + b00), go0 = fsigmoid(acc0[1] + b01);                \
    float gz0 = fsigmoid(acc0[2] + b02), gf0 = fsigmoid(acc0[3] + b03);                \
    c0 = c0 * gf0 + gz0 - gi0;                                                         \
    float hv0 = fsigmoid(c0) - go0;                                                    \
    float gi1 = fsigmoid(acc1[0] + b10), go1 = fsigmoid(acc1[1] + b11);                \
    float gz1 = fsigmoid(acc1[2] + b12), gf1 = fsigmoid(acc1[3] + b13);                \
    c1 = c1 * gf1 + gz1 - gi1;                                                         \
    float hv1 = fsigmoid(c1) - go1;                                                    \
    __hip_atomic_store(hn + hoff0, f2bf(hv0), __ATOMIC_RELAXED, __HIP_MEMORY_SCOPE_AGENT);\
    __hip_atomic_store(hn + hoff1, f2bf(hv1), __ATOMIC_RELAXED, __HIP_MEMORY_SCOPE_AGENT);\
    asm volatile("s_waitcnt vmcnt(0)" ::: "memory");                                   \
    __syncthreads();                                                                   \
    if (tid == 0)                                                                      \
      __hip_atomic_store(myflag + (size_t)((T) + 1) * NWGL + slice, 1,                 \
                         __ATOMIC_RELAXED, __HIP_MEMORY_SCOPE_AGENT);                  \
    if (layer) {                                                                       \
      float* outp = out + (size_t)(T) * ACTMAT;                                        \
      outp[hoff0] = hv0;                                                               \
      outp[hoff1] = hv1;                                                               \
    }                                                                                  \
  } while (0)

  if (layer == 0) {
    for (int t = 0; t < TSTEPS; ++t) {
      f32x4 acc0 = {}, acc1 = {};
      KHALF(xb + (size_t)t * ACTMAT, 0, false);      // x-half: static input, cached loads
      WAIT_FLAGS(flags0 + (size_t)t * NWGL);         // wait for h0[t] (all 64 producers)
      KHALF(h0 + (size_t)t * ACTMAT, 64, true);      // h-half: coherent loads via L3
      EPILOGUE(t);
    }
  } else {
    for (int t = 0; t < TSTEPS; ++t) {
      f32x4 acc0 = {}, acc1 = {};
      WAIT_FLAGS(flags1 + (size_t)t * NWGL);         // own-layer h1[t] (usually ready)
      KHALF(h1 + (size_t)t * ACTMAT, 64, true);
      WAIT_FLAGS(flags0 + (size_t)(t + 1) * NWGL);   // layer0 output h0[t+1] (the late one)
      KHALF(h0 + (size_t)(t + 1) * ACTMAT, 0, true);
      EPILOGUE(t);
    }
  }
#undef KHALF
#undef WAIT_FLAGS
#undef EPILOGUE
}

// ---------------- launch ----------------

extern "C" void kernel_launch(void* const* d_in, const int* in_sizes, int n_in,
                              void* d_out, int out_size, void* d_ws, size_t ws_size,
                              hipStream_t stream) {
  (void)in_sizes; (void)n_in; (void)out_size; (void)ws_size;
  const float* x   = (const float*)d_in[0];
  const float* Wi0 = (const float*)d_in[1];
  const float* bi0 = (const float*)d_in[2];
  const float* Wh0 = (const float*)d_in[3];
  const float* Wi1 = (const float*)d_in[4];
  const float* bi1 = (const float*)d_in[5];
  const float* Wh1 = (const float*)d_in[6];
  float* out = (float*)d_out;

  char* ws = (char*)d_ws;
  size_t off = 0;
  auto take = [&](size_t bytes) -> void* {
    void* p = ws + off;
    off += (bytes + 255) & ~(size_t)255;
    return p;
  };
  unsigned short* xb   = (unsigned short*)take((size_t)TSTEPS * ACTMAT * 2);        // 33.5 MB
  unsigned short* h0   = (unsigned short*)take((size_t)(TSTEPS + 1) * ACTMAT * 2);  // 33.6 MB
  unsigned short* h1   = (unsigned short*)take((size_t)(TSTEPS + 1) * ACTMAT * 2);  // 33.6 MB
  unsigned short* W0hi = (unsigned short*)take((size_t)GATE * 1024 * 2);            // 4 MB x4
  unsigned short* W0lo = (unsigned short*)take((size_t)GATE * 1024 * 2);
  unsigned short* W1hi = (unsigned short*)take((size_t)GATE * 1024 * 2);
  unsigned short* W1lo = (unsigned short*)take((size_t)GATE * 1024 * 2);
  int* flags           = (int*)take((size_t)2 * FSTRIDE * sizeof(int));

  init_buffers<<<dim3(260), dim3(256), 0, stream>>>(h0, h1, flags);
  convert_x<<<dim3(16384), dim3(256), 0, stream>>>(x, xb);
  split_w<<<dim3(8192), dim3(256), 0, stream>>>(Wi0, Wh0, W0hi, W0lo);
  split_w<<<dim3(8192), dim3(256), 0, stream>>>(Wi1, Wh1, W1hi, W1lo);
  sublstm_persistent<<<dim3(128), dim3(256), 0, stream>>>(
      xb, h0, h1, W0hi, W0lo, W1hi, W1lo, bi0, bi1, out, flags);
}

// Round 4
// 5234.281 us; speedup vs baseline: 1.6058x; 1.1060x over previous
//
#include <hip/hip_runtime.h>
#include <stdint.h>

#define TSTEPS 512
#define BATCH  64
#define HDIM   512
#define GATE   2048
#define ACTMAT (BATCH * HDIM)   // 32768 activations per timestep matrix
#define NWGL   64               // workgroups per layer
#define FSTRIDE ((TSTEPS + 1) * 256)   // per-wave flags: 256 per layer-step

typedef __attribute__((ext_vector_type(8))) short bf16x8;
typedef __attribute__((ext_vector_type(4))) float f32x4;
typedef __attribute__((ext_vector_type(4))) uint32_t u32x4;

__device__ __forceinline__ unsigned short f2bf(float f) {
  union { float f; uint32_t u; } v; v.f = f;
  uint32_t r = v.u + 0x7FFFu + ((v.u >> 16) & 1u);   // RNE
  return (unsigned short)(r >> 16);
}
__device__ __forceinline__ float bf2f(unsigned short s) {
  union { uint32_t u; float f; } v; v.u = ((uint32_t)s) << 16;
  return v.f;
}
__device__ __forceinline__ float fsigmoid(float x) {
  return 1.0f / (1.0f + __expf(-x));
}

// ---------------- pre-kernels ----------------

__global__ void init_buffers(unsigned short* h0, unsigned short* h1, int* flags) {
  int i = blockIdx.x * blockDim.x + threadIdx.x;
  if (i < ACTMAT) { h0[i] = 0; h1[i] = 0; }          // h,c initial state = 0
  if (i < 2 * FSTRIDE)                               // re-init flags EVERY launch
    flags[i] = ((i % FSTRIDE) < 256) ? 1 : 0;        // t=0 flags pre-set (h[0] is zeros)
}

__global__ void convert_x(const float* __restrict__ x, unsigned short* __restrict__ xb) {
  size_t i = (size_t)(blockIdx.x * blockDim.x + threadIdx.x) * 4;
  float4 v = *(const float4*)(x + i);
  ushort4 o = make_ushort4(f2bf(v.x), f2bf(v.y), f2bf(v.z), f2bf(v.w));
  *(ushort4*)(xb + i) = o;
}

// Fuse [Wi | Wh] into [GATE][1024]; split each weight into bf16 hi + lo residual.
__global__ void split_w(const float* __restrict__ Wi, const float* __restrict__ Wh,
                        unsigned short* __restrict__ Whi, unsigned short* __restrict__ Wlo) {
  int i = blockIdx.x * blockDim.x + threadIdx.x;     // over GATE*1024
  int G = i >> 10, k = i & 1023;
  float w = (k < 512) ? Wi[((size_t)G << 9) + k] : Wh[((size_t)G << 9) + (k - 512)];
  unsigned short hi = f2bf(w);
  Whi[i] = hi;
  Wlo[i] = f2bf(w - bf2f(hi));
}

// ---------------- persistent recurrence kernel ----------------
// 128 WGs x 256 threads: blockIdx>>6 = layer, blockIdx&63 = slice (8 h-cols, 32 gate rows).
// Transposed GEMM: D[n][b] = sum_k W[n][k]*Act[b][k] via mfma(A=W_frag, B=Act_frag).
// A frag: lane holds A[lane&15][g4*8+j]; B frag: lane holds B[g4*8+j][lane&15] (g4=lane>>4).
// C/D: col=lane&15 -> b, row=4*g4+reg -> n. Gate-row ordering (LDS col n):
//   G(n) = (n&3)*512 + j0 + 2*((n&15)>>2) + (n>>4)
// so lane's 8 acc regs = all 4 gate quadrants of (b, j0+2*g4) and (b, j0+2*g4+1):
// zero-shuffle epilogue + ADJACENT j pair -> one packed 4B h-store / 8B out-store.
// h exchange: L1/L2-bypass (sc0 sc1) loads/stores meeting at coherent memory-side L3.
// This round: bulk-issue the 16 bypass loads per half via inline asm (one vmcnt(0)
// instead of 16 serialized ~600cy round trips), per-wave flags (no producer barrier).

__global__ __launch_bounds__(256, 1)
void sublstm_persistent(const unsigned short* __restrict__ xb,
                        unsigned short* h0, unsigned short* h1,
                        const unsigned short* __restrict__ W0hi, const unsigned short* __restrict__ W0lo,
                        const unsigned short* __restrict__ W1hi, const unsigned short* __restrict__ W1lo,
                        const float* __restrict__ bi0, const float* __restrict__ bi1,
                        float* __restrict__ out, int* flags)
{
  __shared__ unsigned short wlds[2][32][1024];       // 128 KiB: [hi/lo][n][k]

  const int wg    = blockIdx.x;
  const int layer = wg >> 6;
  const int slice = wg & 63;
  const int j0    = slice << 3;                      // first owned h-column
  const int tid   = threadIdx.x;
  const int lane  = tid & 63;
  const int wv    = tid >> 6;                        // wave 0..3 (b-tile)

  const unsigned short* Whi = layer ? W1hi : W0hi;
  const unsigned short* Wlo = layer ? W1lo : W0lo;
  const float* bi = layer ? bi1 : bi0;

  // stage weight slice into LDS (16B units, unit index XOR-swizzled by n&15)
  for (int idx = tid; idx < 8192; idx += 256) {
    int p = idx >> 12;                               // hi/lo panel
    int n = (idx >> 7) & 31;                         // local gate row
    int u = idx & 127;                               // 16B unit within row
    int G = ((n & 3) << 9) + j0 + ((((n & 15) >> 2)) << 1) + (n >> 4);
    const unsigned short* s = (p ? Wlo : Whi) + ((size_t)G << 10) + ((size_t)u << 3);
    *(uint4*)&wlds[p][n][(u ^ (n & 15)) << 3] = *(const uint4*)s;
  }
  __syncthreads();

  const int c15 = lane & 15;
  const int g4  = lane >> 4;
  const int n0 = c15, n1 = 16 + c15;
  const int sw = c15;                                // XOR swizzle key (n0&15 == n1&15)
  const int b    = (wv << 4) + c15;                  // batch row this lane owns
  const int jcol0 = j0 + (g4 << 1);                  // even h-col; pair is (jcol0, jcol0+1)
  const size_t arow = (size_t)b * HDIM;              // activation row offset
  const size_t hoff0 = arow + jcol0;

  const float b00 = bi[jcol0],        b01 = bi[512 + jcol0];
  const float b02 = bi[1024 + jcol0], b03 = bi[1536 + jcol0];
  const float b10 = bi[jcol0 + 1],        b11 = bi[512 + jcol0 + 1];
  const float b12 = bi[1024 + jcol0 + 1], b13 = bi[1536 + jcol0 + 1];

  int* flags0 = flags;
  int* flags1 = flags + FSTRIDE;
  int* myflag = layer ? flags1 : flags0;

  float c0 = 0.0f, c1 = 0.0f;                        // cell state, in regs all 512 steps

#define CONSUME(R, KK) do {                                                            \
    bf16x8 a = __builtin_bit_cast(bf16x8, (R));                                        \
    int u_ = (ub_ + ((KK) << 2) + g4) ^ sw;                                            \
    bf16x8 wh0 = *(const bf16x8*)&wlds[0][n0][u_ << 3];                                \
    bf16x8 wl0 = *(const bf16x8*)&wlds[1][n0][u_ << 3];                                \
    bf16x8 wh1 = *(const bf16x8*)&wlds[0][n1][u_ << 3];                                \
    bf16x8 wl1 = *(const bf16x8*)&wlds[1][n1][u_ << 3];                                \
    acc0 = __builtin_amdgcn_mfma_f32_16x16x32_bf16(wh0, a, acc0, 0, 0, 0);             \
    acc0 = __builtin_amdgcn_mfma_f32_16x16x32_bf16(wl0, a, acc0, 0, 0, 0);             \
    acc1 = __builtin_amdgcn_mfma_f32_16x16x32_bf16(wh1, a, acc1, 0, 0, 0);             \
    acc1 = __builtin_amdgcn_mfma_f32_16x16x32_bf16(wl1, a, acc1, 0, 0, 0);             \
  } while (0)

#define LD1(R, OFFTOK)                                                                 \
    asm volatile("global_load_dwordx4 %0, %1, off " OFFTOK " sc0 sc1"                  \
                 : "=v"(R) : "v"(hp_) : "memory")

// Coherent half: bulk-issue 16 bypass 16B loads, single wait, then 64 MFMAs.
#define KHALF_COH(AP, UBASE) do {                                                      \
    const unsigned short* hp_ = (AP) + arow + (g4 << 3);                               \
    const int ub_ = (UBASE);                                                           \
    u32x4 r0_,r1_,r2_,r3_,r4_,r5_,r6_,r7_,r8_,r9_,r10_,r11_,r12_,r13_,r14_,r15_;       \
    LD1(r0_, "");            LD1(r1_, "offset:64");   LD1(r2_, "offset:128");          \
    LD1(r3_, "offset:192");  LD1(r4_, "offset:256");  LD1(r5_, "offset:320");          \
    LD1(r6_, "offset:384");  LD1(r7_, "offset:448");  LD1(r8_, "offset:512");          \
    LD1(r9_, "offset:576");  LD1(r10_, "offset:640"); LD1(r11_, "offset:704");         \
    LD1(r12_, "offset:768"); LD1(r13_, "offset:832"); LD1(r14_, "offset:896");         \
    LD1(r15_, "offset:960");                                                           \
    asm volatile("s_waitcnt vmcnt(0)" ::: "memory");                                   \
    __builtin_amdgcn_sched_barrier(0);                                                 \
    CONSUME(r0_, 0);  CONSUME(r1_, 1);  CONSUME(r2_, 2);  CONSUME(r3_, 3);             \
    CONSUME(r4_, 4);  CONSUME(r5_, 5);  CONSUME(r6_, 6);  CONSUME(r7_, 7);             \
    CONSUME(r8_, 8);  CONSUME(r9_, 9);  CONSUME(r10_, 10); CONSUME(r11_, 11);          \
    CONSUME(r12_, 12); CONSUME(r13_, 13); CONSUME(r14_, 14); CONSUME(r15_, 15);        \
  } while (0)

// x half: plain cached loads (xb is read-only input, L2-resident per XCD)
#define KHALF_X(AP) do {                                                               \
    const unsigned short* ap_ = (AP) + arow + (g4 << 3);                               \
    const int ub_ = 0;                                                                 \
    _Pragma("unroll")                                                                  \
    for (int kk = 0; kk < 16; ++kk) {                                                  \
      u32x4 rr = *(const u32x4*)(ap_ + (kk << 5));                                     \
      CONSUME(rr, kk);                                                                 \
    }                                                                                  \
  } while (0)

// 256 flags per layer-step; each thread polls exactly one, barrier joins.
#define WAIT_FLAGS(FP) do {                                                            \
    while (__hip_atomic_load((FP) + tid, __ATOMIC_RELAXED,                             \
                             __HIP_MEMORY_SCOPE_AGENT) == 0)                           \
      __builtin_amdgcn_s_sleep(2);                                                     \
    __syncthreads();                                                                   \
  } while (0)

#define EPILOGUE(T) do {                                                               \
    unsigned short* hn = (layer ? h1 : h0) + (size_t)((T) + 1) * ACTMAT;               \
    float gi0 = fsigmoid(acc0[0] + b00), go0 = fsigmoid(acc0[1] + b01);                \
    float gz0 = fsigmoid(acc0[2] + b02), gf0 = fsigmoid(acc0[3] + b03);                \
    c0 = c0 * gf0 + gz0 - gi0;                                                         \
    float hv0 = fsigmoid(c0) - go0;                                                    \
    float gi1 = fsigmoid(acc1[0] + b10), go1 = fsigmoid(acc1[1] + b11);                \
    float gz1 = fsigmoid(acc1[2] + b12), gf1 = fsigmoid(acc1[3] + b13);                \
    c1 = c1 * gf1 + gz1 - gi1;                                                         \
    float hv1 = fsigmoid(c1) - go1;                                                    \
    uint32_t hw = (uint32_t)f2bf(hv0) | ((uint32_t)f2bf(hv1) << 16);                   \
    __hip_atomic_store((uint32_t*)(hn + hoff0), hw, __ATOMIC_RELAXED,                  \
                       __HIP_MEMORY_SCOPE_AGENT);                                      \
    asm volatile("s_waitcnt vmcnt(0)" ::: "memory");  /* wave's h-store at L3 */       \
    if (lane == 0)                                                                     \
      __hip_atomic_store(myflag + (size_t)((T) + 1) * 256 + (slice << 2) + wv, 1,      \
                         __ATOMIC_RELAXED, __HIP_MEMORY_SCOPE_AGENT);                  \
    if (layer) {                                                                       \
      float* outp = out + (size_t)(T) * ACTMAT;                                        \
      *(float2*)(outp + hoff0) = make_float2(hv0, hv1);                                \
    }                                                                                  \
  } while (0)

  if (layer == 0) {
    for (int t = 0; t < TSTEPS; ++t) {
      f32x4 acc0 = {}, acc1 = {};
      KHALF_X(xb + (size_t)t * ACTMAT);              // x-half before the wait (free)
      WAIT_FLAGS(flags0 + (size_t)t * 256);          // h0[t] ready (all 256 waves)
      KHALF_COH(h0 + (size_t)t * ACTMAT, 64);
      EPILOGUE(t);
    }
  } else {
    for (int t = 0; t < TSTEPS; ++t) {
      f32x4 acc0 = {}, acc1 = {};
      WAIT_FLAGS(flags1 + (size_t)t * 256);          // own-layer h1[t] (usually ready)
      KHALF_COH(h1 + (size_t)t * ACTMAT, 64);
      WAIT_FLAGS(flags0 + (size_t)(t + 1) * 256);    // layer0 output (the late one)
      KHALF_COH(h0 + (size_t)(t + 1) * ACTMAT, 0);
      EPILOGUE(t);
    }
  }
#undef CONSUME
#undef LD1
#undef KHALF_COH
#undef KHALF_X
#undef WAIT_FLAGS
#undef EPILOGUE
}

// ---------------- launch ----------------

extern "C" void kernel_launch(void* const* d_in, const int* in_sizes, int n_in,
                              void* d_out, int out_size, void* d_ws, size_t ws_size,
                              hipStream_t stream) {
  (void)in_sizes; (void)n_in; (void)out_size; (void)ws_size;
  const float* x   = (const float*)d_in[0];
  const float* Wi0 = (const float*)d_in[1];
  const float* bi0 = (const float*)d_in[2];
  const float* Wh0 = (const float*)d_in[3];
  const float* Wi1 = (const float*)d_in[4];
  const float* bi1 = (const float*)d_in[5];
  const float* Wh1 = (const float*)d_in[6];
  float* out = (float*)d_out;

  char* ws = (char*)d_ws;
  size_t off = 0;
  auto take = [&](size_t bytes) -> void* {
    void* p = ws + off;
    off += (bytes + 255) & ~(size_t)255;
    return p;
  };
  unsigned short* xb   = (unsigned short*)take((size_t)TSTEPS * ACTMAT * 2);        // 33.5 MB
  unsigned short* h0   = (unsigned short*)take((size_t)(TSTEPS + 1) * ACTMAT * 2);  // 33.6 MB
  unsigned short* h1   = (unsigned short*)take((size_t)(TSTEPS + 1) * ACTMAT * 2);  // 33.6 MB
  unsigned short* W0hi = (unsigned short*)take((size_t)GATE * 1024 * 2);            // 4 MB x4
  unsigned short* W0lo = (unsigned short*)take((size_t)GATE * 1024 * 2);
  unsigned short* W1hi = (unsigned short*)take((size_t)GATE * 1024 * 2);
  unsigned short* W1lo = (unsigned short*)take((size_t)GATE * 1024 * 2);
  int* flags           = (int*)take((size_t)2 * FSTRIDE * sizeof(int));             // ~1 MB

  init_buffers<<<dim3(1032), dim3(256), 0, stream>>>(h0, h1, flags);
  convert_x<<<dim3(16384), dim3(256), 0, stream>>>(x, xb);
  split_w<<<dim3(8192), dim3(256), 0, stream>>>(Wi0, Wh0, W0hi, W0lo);
  split_w<<<dim3(8192), dim3(256), 0, stream>>>(Wi1, Wh1, W1hi, W1lo);
  sublstm_persistent<<<dim3(128), dim3(256), 0, stream>>>(
      xb, h0, h1, W0hi, W0lo, W1hi, W1lo, bi0, bi1, out, flags);
}